// Round 8
// baseline (222.304 us; speedup 1.0000x reference)
//
#include <hip/hip_runtime.h>
#include <hip/hip_bf16.h>

#define DEV __device__ __forceinline__

typedef short short8 __attribute__((ext_vector_type(8)));
typedef float f32x4 __attribute__((ext_vector_type(4)));
typedef unsigned short ushort4v __attribute__((ext_vector_type(4)));
typedef unsigned short u16;

DEV u16 f2b(float x){ __hip_bfloat16 h = __float2bfloat16(x); u16 u; __builtin_memcpy(&u, &h, 2); return u; }

// 128B-row LDS tiles, XOR-swizzled (G4).
DEV int swz(int row, int cb){ return row*128 + (cb ^ ((row & 7) << 4)); }
// 768B-row (384 bf16) LDS tiles, XOR-swizzled.
DEV int swz768(int row, int byte_in_row){ return row*768 + (byte_in_row ^ ((row & 7) << 4)); }

DEV short8 ldfrag(const u16* s, int row, int kbf){
  return *(const short8*)((const char*)s + swz(row, kbf*2));
}
DEV void st16(u16* s, int row, int cb, short8 v){
  *(short8*)((char*)s + swz(row, cb)) = v;
}
DEV f32x4 MFMA(short8 a, short8 b, f32x4 c){
  return __builtin_amdgcn_mfma_f32_16x16x32_bf16(a, b, c, 0, 0, 0);
}

template<int R>
DEV void stage_bf16(u16* lds, const u16* g, size_t rstride, int tid){
  #pragma unroll
  for (int c = tid; c < R*8; c += 256){
    int row = c >> 3, k = c & 7;
    short8 v = *(const short8*)(g + (size_t)row*rstride + k*8);
    st16(lds, row, k*16, v);
  }
}

template<int MI, int NI>
DEV void mma_step(const u16* As, int ar0, const u16* Bs, int br0, f32x4 (&acc)[MI][NI], int lane){
  int r = lane & 15, kb = (lane >> 4) * 8;
  #pragma unroll
  for (int kk = 0; kk < 64; kk += 32){
    short8 a[MI], b[NI];
    #pragma unroll
    for (int mi = 0; mi < MI; ++mi) a[mi] = ldfrag(As, ar0 + mi*16 + r, kk + kb);
    #pragma unroll
    for (int ni = 0; ni < NI; ++ni) b[ni] = ldfrag(Bs, br0 + ni*16 + r, kk + kb);
    #pragma unroll
    for (int mi = 0; mi < MI; ++mi)
      #pragma unroll
      for (int ni = 0; ni < NI; ++ni)
        acc[mi][ni] = MFMA(a[mi], b[ni], acc[mi][ni]);
  }
}

// ---------------- K0: prep — LN->xbf, Wpos->Wpt (transpose), W*->bf16 ----------------
__global__ __launch_bounds__(256) void k_prep(const float* __restrict__ hs,
    const float* __restrict__ lg, const float* __restrict__ lb,
    const float* __restrict__ Wpos, const float* __restrict__ Wq, const float* __restrict__ Wk,
    const float* __restrict__ Wv, const float* __restrict__ Wo,
    u16* __restrict__ xbf, u16* __restrict__ Wpt, u16* __restrict__ Wqb,
    u16* __restrict__ Wkb, u16* __restrict__ Wvb, u16* __restrict__ Wob){
  __shared__ float ws[64][65];
  int bx = blockIdx.x, tid = threadIdx.x;
  if (bx < 64){
    int e0 = (bx & 7) * 64, h = bx >> 3;
    #pragma unroll
    for (int p = tid; p < 64*16; p += 256){
      int d = p >> 4, q = p & 15;
      f32x4 v = *(const f32x4*)(Wpos + (size_t)(h*64 + d)*512 + e0 + q*4);
      #pragma unroll
      for (int t = 0; t < 4; ++t) ws[d][q*4+t] = v[t];
    }
    __syncthreads();
    #pragma unroll
    for (int c = tid; c < 64*8; c += 256){
      int e = c >> 3, dc = c & 7;
      short8 v;
      #pragma unroll
      for (int t = 0; t < 8; ++t) v[t] = (short)f2b(ws[dc*8+t][e]);
      *(short8*)(Wpt + ((size_t)h*512 + e0 + e)*64 + dc*8) = v;
    }
  } else if (bx < 320){
    const float* src[4] = {Wq, Wk, Wv, Wo};
    u16* dst[4] = {Wqb, Wkb, Wvb, Wob};
    int base = (bx - 64) * 4096 + tid * 16;
    int m = base >> 18, off = base & ((1<<18)-1);
    const float* s = src[m] + off;
    u16* d = dst[m] + off;
    #pragma unroll
    for (int hh = 0; hh < 2; ++hh){
      f32x4 a = *(const f32x4*)(s + hh*8);
      f32x4 bb = *(const f32x4*)(s + hh*8 + 4);
      short8 v;
      #pragma unroll
      for (int t = 0; t < 4; ++t){ v[t] = (short)f2b(a[t]); v[t+4] = (short)f2b(bb[t]); }
      *(short8*)(d + hh*8) = v;
    }
  } else {
    int lane = tid & 63, wid = tid >> 6;
    int row = (bx - 320) * 4 + wid;
    const float* p = hs + (size_t)row * 512;
    f32x4 v0 = ((const f32x4*)p)[lane];
    f32x4 v1 = ((const f32x4*)p)[lane + 64];
    float s = 0.f, s2 = 0.f;
    #pragma unroll
    for (int t = 0; t < 4; ++t){ s += v0[t] + v1[t]; s2 += v0[t]*v0[t] + v1[t]*v1[t]; }
    #pragma unroll
    for (int off = 32; off; off >>= 1){ s += __shfl_xor(s, off); s2 += __shfl_xor(s2, off); }
    float mu = s * (1.0f/512.0f);
    float var = s2 * (1.0f/512.0f) - mu*mu;
    float rs = rsqrtf(var + 1e-5f);
    int e0 = lane * 4, e1 = 256 + e0;
    ushort4v o0, o1;
    #pragma unroll
    for (int t = 0; t < 4; ++t){
      o0[t] = f2b((v0[t]-mu)*rs*lg[e0+t]+lb[e0+t]);
      o1[t] = f2b((v1[t]-mu)*rs*lg[e1+t]+lb[e1+t]);
    }
    *(ushort4v*)(xbf + (size_t)row*512 + e0) = o0;
    *(ushort4v*)(xbf + (size_t)row*512 + e1) = o1;
  }
}

// ---------------- K2: QKV projection (all-bf16 staging) ----------------
__global__ __launch_bounds__(256) void k_qkv(const u16* __restrict__ xbf,
    const u16* __restrict__ Wqb, const u16* __restrict__ Wkb, const u16* __restrict__ Wvb,
    const float* __restrict__ bq, const float* __restrict__ bk, const float* __restrict__ bv,
    const float* __restrict__ pbu, const float* __restrict__ pbv,
    u16* __restrict__ qu, u16* __restrict__ qv, u16* __restrict__ kkb, u16* __restrict__ vt){
  __shared__ __align__(16) u16 As[128*64];
  __shared__ __align__(16) u16 Bs[128*64];
  int tid = threadIdx.x, lane = tid & 63, wid = tid >> 6;
  int t0 = blockIdx.x * 128, n0 = blockIdx.y * 128, z = blockIdx.z;
  const u16* Wb     = (z==0) ? Wqb : (z==1) ? Wkb : Wvb;
  const float* bias = (z==0) ? bq  : (z==1) ? bk  : bv;
  f32x4 acc[4][4] = {};
  for (int k0 = 0; k0 < 512; k0 += 64){
    stage_bf16<128>(As, xbf + (size_t)t0*512 + k0, 512, tid);
    stage_bf16<128>(Bs, Wb + (size_t)n0*512 + k0, 512, tid);
    __syncthreads();
    mma_step<4,4>(As, (wid>>1)*64, Bs, (wid&1)*64, acc, lane);
    __syncthreads();
  }
  int r = lane & 15, half = lane >> 4;
  #pragma unroll
  for (int mi = 0; mi < 4; ++mi)
  #pragma unroll
  for (int ni = 0; ni < 4; ++ni){
    int n = n0 + (wid&1)*64 + ni*16 + r;
    int h = n >> 6, d = n & 63;
    int m0 = t0 + (wid>>1)*64 + mi*16 + half*4;
    #pragma unroll
    for (int q = 0; q < 4; ++q){
      int t = m0 + q, b = t / 384, i = t - b*384;
      float v = acc[mi][ni][q] + bias[n];
      if (z == 0){
        qu[((size_t)(b*8+h)*384 + i)*64 + d] = f2b(v + pbu[n]);
        qv[((size_t)h*3072 + t)*64 + d]      = f2b(v + pbv[n]);
      } else if (z == 1){
        kkb[((size_t)(b*8+h)*384 + i)*64 + d] = f2b(v);
      } else {
        vt[((size_t)(b*8+h)*64 + d)*384 + i] = f2b(v);
      }
    }
  }
}

// ---------------- K3: qW[bh][j][e] = q_v[h] @ Wpt[h]^T  (K=64) ----------------
__global__ __launch_bounds__(256) void k_qw(const u16* __restrict__ qv, const u16* __restrict__ Wpt,
                                            u16* __restrict__ qW){
  __shared__ __align__(16) u16 As[128*64];
  __shared__ __align__(16) u16 Bs[128*64];
  int tid = threadIdx.x, lane = tid & 63, wid = tid >> 6;
  int t0 = blockIdx.x * 128, e0 = blockIdx.y * 128, h = blockIdx.z;
  f32x4 acc[4][4] = {};
  stage_bf16<128>(As, qv + ((size_t)h*3072 + t0)*64, 64, tid);
  stage_bf16<128>(Bs, Wpt + ((size_t)h*512 + e0)*64, 64, tid);
  __syncthreads();
  mma_step<4,4>(As, (wid>>1)*64, Bs, (wid&1)*64, acc, lane);
  int r = lane & 15, half = lane >> 4;
  #pragma unroll
  for (int mi = 0; mi < 4; ++mi)
  #pragma unroll
  for (int ni = 0; ni < 4; ++ni){
    int e = e0 + (wid&1)*64 + ni*16 + r;
    int m0 = t0 + (wid>>1)*64 + mi*16 + half*4;
    #pragma unroll
    for (int q = 0; q < 4; ++q){
      int t = m0 + q, b = t / 384, j = t - b*384;
      int bh = b*8 + h;
      qW[((size_t)bh*384 + j)*512 + e] = f2b(acc[mi][ni][q]);
    }
  }
}

// ---------------- K5: BD scores per (i-half, j): Sbd[j][bh][i] ----------------
__global__ __launch_bounds__(256, 3) void k_bd(const u16* __restrict__ qW, const float* __restrict__ P,
                                               float* __restrict__ Sbd){
  __shared__ __align__(16) u16 As[64*256];
  int tid = threadIdx.x, lane = tid & 63, wid = tid >> 6;
  int r = lane & 15, half = lane >> 4;
  int ib = blockIdx.x * 192, j = blockIdx.y;

  const float* Bp[3];
  #pragma unroll
  for (int ni = 0; ni < 3; ++ni){
    int i = ib + wid*48 + ni*16 + r;
    Bp[ni] = P + ((size_t)i*384 + j)*512 + half*8;
  }
  const u16* Ag = qW + (size_t)j*512;

  f32x4 acc[4][3] = {};
  #pragma unroll
  for (int kh = 0; kh < 2; ++kh){
    if (kh) __syncthreads();
    #pragma unroll
    for (int s = 0; s < 8; ++s){
      int c = tid + s*256;
      int bh = c >> 5, c16 = c & 31;
      short8 v = *(const short8*)(Ag + (size_t)bh*(384*512) + kh*256 + c16*8);
      *(short8*)((char*)As + bh*512 + ((c16*16) ^ ((bh & 7) << 4))) = v;
    }
    __syncthreads();
    #pragma unroll
    for (int k32 = 0; k32 < 8; ++k32){
      int e0 = kh*256 + k32*32;
      short8 bfr[3];
      #pragma unroll
      for (int ni = 0; ni < 3; ++ni){
        f32x4 f0 = *(const f32x4*)(Bp[ni] + e0);
        f32x4 f1 = *(const f32x4*)(Bp[ni] + e0 + 4);
        #pragma unroll
        for (int t = 0; t < 4; ++t){ bfr[ni][t] = (short)f2b(f0[t]); bfr[ni][t+4] = (short)f2b(f1[t]); }
      }
      #pragma unroll
      for (int mi = 0; mi < 4; ++mi){
        int row = mi*16 + r;
        short8 afr = *(const short8*)((const char*)As + row*512 + ((k32*64 + half*16) ^ ((row & 7) << 4)));
        #pragma unroll
        for (int ni = 0; ni < 3; ++ni)
          acc[mi][ni] = MFMA(afr, bfr[ni], acc[mi][ni]);
      }
    }
  }
  #pragma unroll
  for (int mi = 0; mi < 4; ++mi)
  #pragma unroll
  for (int ni = 0; ni < 3; ++ni){
    int i = ib + wid*48 + ni*16 + r;
    #pragma unroll
    for (int q = 0; q < 4; ++q){
      int bh = mi*16 + half*4 + q;
      Sbd[((size_t)j*64 + bh)*384 + i] = acc[mi][ni][q];
    }
  }
}

// ---------------- K6: fused AC + softmax + PV, 512 threads (8 waves = 2/SIMD) ----------------
__global__ __launch_bounds__(512) void k_fin(const u16* __restrict__ qu, const u16* __restrict__ kkb,
                                             const u16* __restrict__ vt, const float* __restrict__ Sbd,
                                             const int* __restrict__ mask, u16* __restrict__ ctx){
  __shared__ __align__(16) u16 Ks[384*64];
  __shared__ __align__(16) u16 Qs[96*64];
  __shared__ __align__(16) u16 Vs[64*384];
  __shared__ __align__(16) u16 Ps[32*384];
  __shared__ float smbuf[2][8][2][16];
  int tid = threadIdx.x, lane = tid & 63, wid = tid >> 6;
  int r = lane & 15, half = lane >> 4;
  int i0 = blockIdx.x * 96, bh = blockIdx.y, b = bh >> 3, h = bh & 7;

  #pragma unroll
  for (int c = tid; c < 3072; c += 512){
    int row = c >> 3, k = c & 7;
    short8 v = *(const short8*)(kkb + ((size_t)bh*384 + row)*64 + k*8);
    st16(Ks, row, k*16, v);
  }
  #pragma unroll
  for (int c = tid; c < 768; c += 512){
    int row = c >> 3, k = c & 7;
    short8 v = *(const short8*)(qu + ((size_t)bh*384 + i0 + row)*64 + k*8);
    st16(Qs, row, k*16, v);
  }
  #pragma unroll
  for (int c = tid; c < 3072; c += 512){
    int d = c / 48, jc = c - d*48;
    short8 v = *(const short8*)(vt + ((size_t)bh*64 + d)*384 + jc*8);
    *(short8*)((char*)Vs + swz768(d, jc*16)) = v;
  }
  __syncthreads();

  for (int sub = 0; sub < 3; ++sub){
    int i0s = i0 + sub*32;
    f32x4 acc[3][2] = {};
    mma_step<3,2>(Ks, wid*48, Qs, sub*32, acc, lane);

    int jw = wid*48 + half*4;
    #pragma unroll
    for (int mi = 0; mi < 3; ++mi){
      #pragma unroll
      for (int q = 0; q < 4; ++q){
        int j = jw + mi*16 + q;
        bool dead = (mask[b*384 + j] == 0);
        const float* srow = Sbd + ((size_t)j*64 + bh)*384 + i0s;
        #pragma unroll
        for (int ni = 0; ni < 2; ++ni){
          float v = (acc[mi][ni][q] + srow[ni*16 + r]) * 0.125f;
          acc[mi][ni][q] = dead ? -3.402823466e38f : v;
        }
      }
    }

    float mx[2];
    #pragma unroll
    for (int ni = 0; ni < 2; ++ni){
      float m = -3.402823466e38f;
      #pragma unroll
      for (int mi = 0; mi < 3; ++mi){
        f32x4 a = acc[mi][ni];
        m = fmaxf(m, fmaxf(fmaxf(a[0],a[1]), fmaxf(a[2],a[3])));
      }
      m = fmaxf(m, __shfl_xor(m, 16));
      m = fmaxf(m, __shfl_xor(m, 32));
      mx[ni] = m;
    }
    if (lane < 16){ smbuf[0][wid][0][r] = mx[0]; smbuf[0][wid][1][r] = mx[1]; }
    __syncthreads();
    #pragma unroll
    for (int ni = 0; ni < 2; ++ni){
      float m = smbuf[0][0][ni][r];
      #pragma unroll
      for (int w = 1; w < 8; ++w) m = fmaxf(m, smbuf[0][w][ni][r]);
      mx[ni] = m;
    }

    float sum[2] = {0.f, 0.f};
    #pragma unroll
    for (int ni = 0; ni < 2; ++ni){
      #pragma unroll
      for (int mi = 0; mi < 3; ++mi)
        #pragma unroll
        for (int q = 0; q < 4; ++q){
          float e = __expf(acc[mi][ni][q] - mx[ni]);
          acc[mi][ni][q] = e; sum[ni] += e;
        }
      sum[ni] += __shfl_xor(sum[ni], 16);
      sum[ni] += __shfl_xor(sum[ni], 32);
    }
    if (lane < 16){ smbuf[1][wid][0][r] = sum[0]; smbuf[1][wid][1][r] = sum[1]; }
    __syncthreads();
    float inv[2];
    #pragma unroll
    for (int ni = 0; ni < 2; ++ni){
      float s = smbuf[1][0][ni][r];
      #pragma unroll
      for (int w = 1; w < 8; ++w) s += smbuf[1][w][ni][r];
      inv[ni] = 1.0f / s;
    }

    #pragma unroll
    for (int mi = 0; mi < 3; ++mi){
      int jb = jw + mi*16;
      #pragma unroll
      for (int ni = 0; ni < 2; ++ni){
        int i = ni*16 + r;
        ushort4v pk;
        #pragma unroll
        for (int q = 0; q < 4; ++q) pk[q] = f2b(acc[mi][ni][q] * inv[ni]);
        *(ushort4v*)((char*)Ps + swz768(i, jb*2)) = pk;
      }
    }
    __syncthreads();

    int mih = wid >> 2, dq = wid & 3;
    f32x4 acc2 = {};
    #pragma unroll
    for (int ks = 0; ks < 384; ks += 32){
      int j0 = ks + half*8;
      short8 bfr = *(const short8*)((const char*)Vs + swz768(dq*16 + r, j0*2));
      short8 afr = *(const short8*)((const char*)Ps + swz768(mih*16 + r, j0*2));
      acc2 = MFMA(afr, bfr, acc2);
    }
    #pragma unroll
    for (int q = 0; q < 4; ++q){
      int i = i0s + mih*16 + half*4 + q;
      int d = dq*16 + r;
      ctx[((size_t)(b*384 + i))*512 + h*64 + d] = f2b(acc2[q]);
    }
  }
}

// ---------------- K8: out = ctx @ Wo^T + bo (fp32 out), 64x64 tiles, bf16 staging ----------------
__global__ __launch_bounds__(256) void k_out(const u16* __restrict__ ctx, const u16* __restrict__ Wob,
                                             const float* __restrict__ bo, float* __restrict__ out){
  __shared__ __align__(16) u16 As[64*64];
  __shared__ __align__(16) u16 Bs[64*64];
  int tid = threadIdx.x, lane = tid & 63, wid = tid >> 6;
  int t0 = blockIdx.x * 64, n0 = blockIdx.y * 64;
  f32x4 acc[2][2] = {};
  for (int k0 = 0; k0 < 512; k0 += 64){
    stage_bf16<64>(As, ctx + (size_t)t0*512 + k0, 512, tid);
    stage_bf16<64>(Bs, Wob + (size_t)n0*512 + k0, 512, tid);
    __syncthreads();
    mma_step<2,2>(As, (wid>>1)*32, Bs, (wid&1)*32, acc, lane);
    __syncthreads();
  }
  int r = lane & 15, half = lane >> 4;
  #pragma unroll
  for (int mi = 0; mi < 2; ++mi)
  #pragma unroll
  for (int ni = 0; ni < 2; ++ni){
    int n = n0 + (wid&1)*32 + ni*16 + r;
    int m0 = t0 + (wid>>1)*32 + mi*16 + half*4;
    #pragma unroll
    for (int q = 0; q < 4; ++q){
      int t = m0 + q;
      out[(size_t)t*512 + n] = acc[mi][ni][q] + bo[n];
    }
  }
}

extern "C" void kernel_launch(void* const* d_in, const int* in_sizes, int n_in,
                              void* d_out, int out_size, void* d_ws, size_t ws_size,
                              hipStream_t stream) {
  const float* hs   = (const float*)d_in[0];
  const float* P    = (const float*)d_in[1];
  const int*   mask = (const int*)d_in[2];
  const float* ln_g = (const float*)d_in[3];
  const float* ln_b = (const float*)d_in[4];
  const float* Wq   = (const float*)d_in[5];
  const float* bq   = (const float*)d_in[6];
  const float* Wk   = (const float*)d_in[7];
  const float* bk   = (const float*)d_in[8];
  const float* Wv   = (const float*)d_in[9];
  const float* bv   = (const float*)d_in[10];
  const float* Wpos = (const float*)d_in[11];
  const float* pbu  = (const float*)d_in[12];
  const float* pbv  = (const float*)d_in[13];
  const float* Wo   = (const float*)d_in[14];
  const float* bo   = (const float*)d_in[15];
  float* out = (float*)d_out;

  char* w = (char*)d_ws;
  u16* xbf = (u16*)w;   w += (size_t)3072*512*2;
  u16* qu  = (u16*)w;   w += (size_t)3072*512*2;
  u16* qv  = (u16*)w;   w += (size_t)3072*512*2;
  u16* kkb = (u16*)w;   w += (size_t)3072*512*2;
  u16* vt  = (u16*)w;   w += (size_t)3072*512*2;
  u16* Wpt = (u16*)w;   w += (size_t)8*512*64*2;
  u16* Wqb = (u16*)w;   w += (size_t)512*512*2;
  u16* Wkb = (u16*)w;   w += (size_t)512*512*2;
  u16* Wvb = (u16*)w;   w += (size_t)512*512*2;
  u16* Wob = (u16*)w;   w += (size_t)512*512*2;
  u16* ctx = (u16*)w;   w += (size_t)3072*512*2;
  u16* qW  = (u16*)w;   w += (size_t)64*384*512*2;
  float* Sbd = (float*)w; w += (size_t)64*384*384*4;

  // DIAGNOSTIC: every non-bd kernel launched TWICE (all idempotent).
  // rest_total = dur(this round) - 158.7
  k_prep<<<1088, 256, 0, stream>>>(hs, ln_g, ln_b, Wpos, Wq, Wk, Wv, Wo,
                                   xbf, Wpt, Wqb, Wkb, Wvb, Wob);
  k_prep<<<1088, 256, 0, stream>>>(hs, ln_g, ln_b, Wpos, Wq, Wk, Wv, Wo,
                                   xbf, Wpt, Wqb, Wkb, Wvb, Wob);
  k_qkv<<<dim3(24,4,3), 256, 0, stream>>>(xbf, Wqb, Wkb, Wvb, bq, bk, bv, pbu, pbv, qu, qv, kkb, vt);
  k_qkv<<<dim3(24,4,3), 256, 0, stream>>>(xbf, Wqb, Wkb, Wvb, bq, bk, bv, pbu, pbv, qu, qv, kkb, vt);
  k_qw <<<dim3(24,4,8), 256, 0, stream>>>(qv, Wpt, qW);
  k_qw <<<dim3(24,4,8), 256, 0, stream>>>(qv, Wpt, qW);
  k_bd <<<dim3(2,384), 256, 0, stream>>>(qW, P, Sbd);
  k_fin<<<dim3(4,64), 512, 0, stream>>>(qu, kkb, vt, Sbd, mask, ctx);
  k_fin<<<dim3(4,64), 512, 0, stream>>>(qu, kkb, vt, Sbd, mask, ctx);
  k_out<<<dim3(48,8), 256, 0, stream>>>(ctx, Wob, bo, out);
  k_out<<<dim3(48,8), 256, 0, stream>>>(ctx, Wob, bo, out);
}

// Round 9
// 164.984 us; speedup vs baseline: 1.3474x; 1.3474x over previous
//
#include <hip/hip_runtime.h>
#include <hip/hip_bf16.h>

#define DEV __device__ __forceinline__

typedef short short8 __attribute__((ext_vector_type(8)));
typedef float f32x4 __attribute__((ext_vector_type(4)));
typedef unsigned short ushort4v __attribute__((ext_vector_type(4)));
typedef unsigned short u16;

DEV u16 f2b(float x){ __hip_bfloat16 h = __float2bfloat16(x); u16 u; __builtin_memcpy(&u, &h, 2); return u; }

// 128B-row LDS tiles, XOR-swizzled (G4).
DEV int swz(int row, int cb){ return row*128 + (cb ^ ((row & 7) << 4)); }
// 768B-row (384 bf16) LDS tiles, XOR-swizzled.
DEV int swz768(int row, int byte_in_row){ return row*768 + (byte_in_row ^ ((row & 7) << 4)); }

DEV short8 ldfrag(const u16* s, int row, int kbf){
  return *(const short8*)((const char*)s + swz(row, kbf*2));
}
DEV void st16(u16* s, int row, int cb, short8 v){
  *(short8*)((char*)s + swz(row, cb)) = v;
}
DEV f32x4 MFMA(short8 a, short8 b, f32x4 c){
  return __builtin_amdgcn_mfma_f32_16x16x32_bf16(a, b, c, 0, 0, 0);
}

template<int R>
DEV void stage_bf16(u16* lds, const u16* g, size_t rstride, int tid){
  #pragma unroll
  for (int c = tid; c < R*8; c += 256){
    int row = c >> 3, k = c & 7;
    short8 v = *(const short8*)(g + (size_t)row*rstride + k*8);
    st16(lds, row, k*16, v);
  }
}

template<int MI, int NI>
DEV void mma_step(const u16* As, int ar0, const u16* Bs, int br0, f32x4 (&acc)[MI][NI], int lane){
  int r = lane & 15, kb = (lane >> 4) * 8;
  #pragma unroll
  for (int kk = 0; kk < 64; kk += 32){
    short8 a[MI], b[NI];
    #pragma unroll
    for (int mi = 0; mi < MI; ++mi) a[mi] = ldfrag(As, ar0 + mi*16 + r, kk + kb);
    #pragma unroll
    for (int ni = 0; ni < NI; ++ni) b[ni] = ldfrag(Bs, br0 + ni*16 + r, kk + kb);
    #pragma unroll
    for (int mi = 0; mi < MI; ++mi)
      #pragma unroll
      for (int ni = 0; ni < NI; ++ni)
        acc[mi][ni] = MFMA(a[mi], b[ni], acc[mi][ni]);
  }
}

// ---------------- K0: prep — LN->xbf, Wpos->Wpt (transpose), W*->bf16 ----------------
__global__ __launch_bounds__(256) void k_prep(const float* __restrict__ hs,
    const float* __restrict__ lg, const float* __restrict__ lb,
    const float* __restrict__ Wpos, const float* __restrict__ Wq, const float* __restrict__ Wk,
    const float* __restrict__ Wv, const float* __restrict__ Wo,
    u16* __restrict__ xbf, u16* __restrict__ Wpt, u16* __restrict__ Wqb,
    u16* __restrict__ Wkb, u16* __restrict__ Wvb, u16* __restrict__ Wob){
  __shared__ float ws[64][65];
  int bx = blockIdx.x, tid = threadIdx.x;
  if (bx < 64){
    int e0 = (bx & 7) * 64, h = bx >> 3;
    #pragma unroll
    for (int p = tid; p < 64*16; p += 256){
      int d = p >> 4, q = p & 15;
      f32x4 v = *(const f32x4*)(Wpos + (size_t)(h*64 + d)*512 + e0 + q*4);
      #pragma unroll
      for (int t = 0; t < 4; ++t) ws[d][q*4+t] = v[t];
    }
    __syncthreads();
    #pragma unroll
    for (int c = tid; c < 64*8; c += 256){
      int e = c >> 3, dc = c & 7;
      short8 v;
      #pragma unroll
      for (int t = 0; t < 8; ++t) v[t] = (short)f2b(ws[dc*8+t][e]);
      *(short8*)(Wpt + ((size_t)h*512 + e0 + e)*64 + dc*8) = v;
    }
  } else if (bx < 320){
    const float* src[4] = {Wq, Wk, Wv, Wo};
    u16* dst[4] = {Wqb, Wkb, Wvb, Wob};
    int base = (bx - 64) * 4096 + tid * 16;
    int m = base >> 18, off = base & ((1<<18)-1);
    const float* s = src[m] + off;
    u16* d = dst[m] + off;
    #pragma unroll
    for (int hh = 0; hh < 2; ++hh){
      f32x4 a = *(const f32x4*)(s + hh*8);
      f32x4 bb = *(const f32x4*)(s + hh*8 + 4);
      short8 v;
      #pragma unroll
      for (int t = 0; t < 4; ++t){ v[t] = (short)f2b(a[t]); v[t+4] = (short)f2b(bb[t]); }
      *(short8*)(d + hh*8) = v;
    }
  } else {
    int lane = tid & 63, wid = tid >> 6;
    int row = (bx - 320) * 4 + wid;
    const float* p = hs + (size_t)row * 512;
    f32x4 v0 = ((const f32x4*)p)[lane];
    f32x4 v1 = ((const f32x4*)p)[lane + 64];
    float s = 0.f, s2 = 0.f;
    #pragma unroll
    for (int t = 0; t < 4; ++t){ s += v0[t] + v1[t]; s2 += v0[t]*v0[t] + v1[t]*v1[t]; }
    #pragma unroll
    for (int off = 32; off; off >>= 1){ s += __shfl_xor(s, off); s2 += __shfl_xor(s2, off); }
    float mu = s * (1.0f/512.0f);
    float var = s2 * (1.0f/512.0f) - mu*mu;
    float rs = rsqrtf(var + 1e-5f);
    int e0 = lane * 4, e1 = 256 + e0;
    ushort4v o0, o1;
    #pragma unroll
    for (int t = 0; t < 4; ++t){
      o0[t] = f2b((v0[t]-mu)*rs*lg[e0+t]+lb[e0+t]);
      o1[t] = f2b((v1[t]-mu)*rs*lg[e1+t]+lb[e1+t]);
    }
    *(ushort4v*)(xbf + (size_t)row*512 + e0) = o0;
    *(ushort4v*)(xbf + (size_t)row*512 + e1) = o1;
  }
}

// ---------------- K2: QKV projection (all-bf16 staging) ----------------
__global__ __launch_bounds__(256) void k_qkv(const u16* __restrict__ xbf,
    const u16* __restrict__ Wqb, const u16* __restrict__ Wkb, const u16* __restrict__ Wvb,
    const float* __restrict__ bq, const float* __restrict__ bk, const float* __restrict__ bv,
    const float* __restrict__ pbu, const float* __restrict__ pbv,
    u16* __restrict__ qu, u16* __restrict__ qv, u16* __restrict__ kkb, u16* __restrict__ vt){
  __shared__ __align__(16) u16 As[128*64];
  __shared__ __align__(16) u16 Bs[128*64];
  int tid = threadIdx.x, lane = tid & 63, wid = tid >> 6;
  int t0 = blockIdx.x * 128, n0 = blockIdx.y * 128, z = blockIdx.z;
  const u16* Wb     = (z==0) ? Wqb : (z==1) ? Wkb : Wvb;
  const float* bias = (z==0) ? bq  : (z==1) ? bk  : bv;
  f32x4 acc[4][4] = {};
  for (int k0 = 0; k0 < 512; k0 += 64){
    stage_bf16<128>(As, xbf + (size_t)t0*512 + k0, 512, tid);
    stage_bf16<128>(Bs, Wb + (size_t)n0*512 + k0, 512, tid);
    __syncthreads();
    mma_step<4,4>(As, (wid>>1)*64, Bs, (wid&1)*64, acc, lane);
    __syncthreads();
  }
  int r = lane & 15, half = lane >> 4;
  #pragma unroll
  for (int mi = 0; mi < 4; ++mi)
  #pragma unroll
  for (int ni = 0; ni < 4; ++ni){
    int n = n0 + (wid&1)*64 + ni*16 + r;
    int h = n >> 6, d = n & 63;
    int m0 = t0 + (wid>>1)*64 + mi*16 + half*4;
    #pragma unroll
    for (int q = 0; q < 4; ++q){
      int t = m0 + q, b = t / 384, i = t - b*384;
      float v = acc[mi][ni][q] + bias[n];
      if (z == 0){
        qu[((size_t)(b*8+h)*384 + i)*64 + d] = f2b(v + pbu[n]);
        qv[((size_t)h*3072 + t)*64 + d]      = f2b(v + pbv[n]);
      } else if (z == 1){
        kkb[((size_t)(b*8+h)*384 + i)*64 + d] = f2b(v);
      } else {
        vt[((size_t)(b*8+h)*64 + d)*384 + i] = f2b(v);
      }
    }
  }
}

// ---------------- K3: qW[bh][j][e] = q_v[h] @ Wpt[h]^T  (K=64) ----------------
__global__ __launch_bounds__(256) void k_qw(const u16* __restrict__ qv, const u16* __restrict__ Wpt,
                                            u16* __restrict__ qW){
  __shared__ __align__(16) u16 As[128*64];
  __shared__ __align__(16) u16 Bs[128*64];
  int tid = threadIdx.x, lane = tid & 63, wid = tid >> 6;
  int t0 = blockIdx.x * 128, e0 = blockIdx.y * 128, h = blockIdx.z;
  f32x4 acc[4][4] = {};
  stage_bf16<128>(As, qv + ((size_t)h*3072 + t0)*64, 64, tid);
  stage_bf16<128>(Bs, Wpt + ((size_t)h*512 + e0)*64, 64, tid);
  __syncthreads();
  mma_step<4,4>(As, (wid>>1)*64, Bs, (wid&1)*64, acc, lane);
  int r = lane & 15, half = lane >> 4;
  #pragma unroll
  for (int mi = 0; mi < 4; ++mi)
  #pragma unroll
  for (int ni = 0; ni < 4; ++ni){
    int e = e0 + (wid&1)*64 + ni*16 + r;
    int m0 = t0 + (wid>>1)*64 + mi*16 + half*4;
    #pragma unroll
    for (int q = 0; q < 4; ++q){
      int t = m0 + q, b = t / 384, j = t - b*384;
      int bh = b*8 + h;
      qW[((size_t)bh*384 + j)*512 + e] = f2b(acc[mi][ni][q]);
    }
  }
}

// ---------------- K5: BD scores per (i-half, j): Sbd[j][bh][i] ----------------
__global__ __launch_bounds__(256, 3) void k_bd(const u16* __restrict__ qW, const float* __restrict__ P,
                                               float* __restrict__ Sbd){
  __shared__ __align__(16) u16 As[64*256];
  int tid = threadIdx.x, lane = tid & 63, wid = tid >> 6;
  int r = lane & 15, half = lane >> 4;
  int ib = blockIdx.x * 192, j = blockIdx.y;

  const float* Bp[3];
  #pragma unroll
  for (int ni = 0; ni < 3; ++ni){
    int i = ib + wid*48 + ni*16 + r;
    Bp[ni] = P + ((size_t)i*384 + j)*512 + half*8;
  }
  const u16* Ag = qW + (size_t)j*512;

  f32x4 acc[4][3] = {};
  #pragma unroll
  for (int kh = 0; kh < 2; ++kh){
    if (kh) __syncthreads();
    #pragma unroll
    for (int s = 0; s < 8; ++s){
      int c = tid + s*256;
      int bh = c >> 5, c16 = c & 31;
      short8 v = *(const short8*)(Ag + (size_t)bh*(384*512) + kh*256 + c16*8);
      *(short8*)((char*)As + bh*512 + ((c16*16) ^ ((bh & 7) << 4))) = v;
    }
    __syncthreads();
    #pragma unroll
    for (int k32 = 0; k32 < 8; ++k32){
      int e0 = kh*256 + k32*32;
      short8 bfr[3];
      #pragma unroll
      for (int ni = 0; ni < 3; ++ni){
        f32x4 f0 = *(const f32x4*)(Bp[ni] + e0);
        f32x4 f1 = *(const f32x4*)(Bp[ni] + e0 + 4);
        #pragma unroll
        for (int t = 0; t < 4; ++t){ bfr[ni][t] = (short)f2b(f0[t]); bfr[ni][t+4] = (short)f2b(f1[t]); }
      }
      #pragma unroll
      for (int mi = 0; mi < 4; ++mi){
        int row = mi*16 + r;
        short8 afr = *(const short8*)((const char*)As + row*512 + ((k32*64 + half*16) ^ ((row & 7) << 4)));
        #pragma unroll
        for (int ni = 0; ni < 3; ++ni)
          acc[mi][ni] = MFMA(afr, bfr[ni], acc[mi][ni]);
      }
    }
  }
  #pragma unroll
  for (int mi = 0; mi < 4; ++mi)
  #pragma unroll
  for (int ni = 0; ni < 3; ++ni){
    int i = ib + wid*48 + ni*16 + r;
    #pragma unroll
    for (int q = 0; q < 4; ++q){
      int bh = mi*16 + half*4 + q;
      Sbd[((size_t)j*64 + bh)*384 + i] = acc[mi][ni][q];
    }
  }
}

// ---------------- K6: fused AC + softmax + PV, 512 threads ----------------
// QK^T uses A=Q, B=K so C has i on (half,q), j on r: Sbd ingested as f32x4.
__global__ __launch_bounds__(512) void k_fin(const u16* __restrict__ qu, const u16* __restrict__ kkb,
                                             const u16* __restrict__ vt, const float* __restrict__ Sbd,
                                             const int* __restrict__ mask, u16* __restrict__ ctx){
  __shared__ __align__(16) u16 Ks[384*64];
  __shared__ __align__(16) u16 Qs[96*64];
  __shared__ __align__(16) u16 Vs[64*384];
  __shared__ __align__(16) u16 Ps[32*384];
  __shared__ float smbuf[2][8][32];
  int tid = threadIdx.x, lane = tid & 63, wid = tid >> 6;
  int r = lane & 15, half = lane >> 4;
  int i0 = blockIdx.x * 96, bh = blockIdx.y, b = bh >> 3, h = bh & 7;

  #pragma unroll
  for (int c = tid; c < 3072; c += 512){
    int row = c >> 3, k = c & 7;
    short8 v = *(const short8*)(kkb + ((size_t)bh*384 + row)*64 + k*8);
    st16(Ks, row, k*16, v);
  }
  #pragma unroll
  for (int c = tid; c < 768; c += 512){
    int row = c >> 3, k = c & 7;
    short8 v = *(const short8*)(qu + ((size_t)bh*384 + i0 + row)*64 + k*8);
    st16(Qs, row, k*16, v);
  }
  #pragma unroll
  for (int c = tid; c < 3072; c += 512){
    int d = c / 48, jc = c - d*48;
    short8 v = *(const short8*)(vt + ((size_t)bh*64 + d)*384 + jc*8);
    *(short8*)((char*)Vs + swz768(d, jc*16)) = v;
  }
  __syncthreads();

  for (int sub = 0; sub < 3; ++sub){
    int i0s = i0 + sub*32;
    f32x4 acc[2][3] = {};
    // A = Q rows (i), B = K rows (j): i = i0s + mi*16 + half*4 + q, j = wid*48 + ni*16 + r
    mma_step<2,3>(Qs, sub*32, Ks, wid*48, acc, lane);

    // add BD scores (f32x4), mask, scale
    #pragma unroll
    for (int ni = 0; ni < 3; ++ni){
      int j = wid*48 + ni*16 + r;
      bool dead = (mask[b*384 + j] == 0);
      const float* sp = Sbd + ((size_t)j*64 + bh)*384 + i0s;
      #pragma unroll
      for (int mi = 0; mi < 2; ++mi){
        f32x4 sv = *(const f32x4*)(sp + mi*16 + half*4);
        #pragma unroll
        for (int q = 0; q < 4; ++q){
          float v = (acc[mi][ni][q] + sv[q]) * 0.125f;
          acc[mi][ni][q] = dead ? -3.402823466e38f : v;
        }
      }
    }

    // row max over j: in-lane (ni) + 16-lane shfl (r) + cross-wave via smbuf
    f32x4 mx[2];
    #pragma unroll
    for (int mi = 0; mi < 2; ++mi){
      f32x4 m = acc[mi][0];
      #pragma unroll
      for (int ni = 1; ni < 3; ++ni)
        #pragma unroll
        for (int q = 0; q < 4; ++q) m[q] = fmaxf(m[q], acc[mi][ni][q]);
      #pragma unroll
      for (int off = 1; off < 16; off <<= 1)
        #pragma unroll
        for (int q = 0; q < 4; ++q) m[q] = fmaxf(m[q], __shfl_xor(m[q], off));
      mx[mi] = m;
    }
    if (r == 0){
      #pragma unroll
      for (int mi = 0; mi < 2; ++mi)
        #pragma unroll
        for (int q = 0; q < 4; ++q)
          smbuf[0][wid][mi*16 + half*4 + q] = mx[mi][q];
    }
    __syncthreads();
    #pragma unroll
    for (int mi = 0; mi < 2; ++mi)
      #pragma unroll
      for (int q = 0; q < 4; ++q){
        int il = mi*16 + half*4 + q;
        float m = smbuf[0][0][il];
        #pragma unroll
        for (int w2 = 1; w2 < 8; ++w2) m = fmaxf(m, smbuf[0][w2][il]);
        mx[mi][q] = m;
      }

    // exp + sum
    f32x4 sm[2];
    #pragma unroll
    for (int mi = 0; mi < 2; ++mi){
      f32x4 s = {};
      #pragma unroll
      for (int ni = 0; ni < 3; ++ni)
        #pragma unroll
        for (int q = 0; q < 4; ++q){
          float e = __expf(acc[mi][ni][q] - mx[mi][q]);
          acc[mi][ni][q] = e; s[q] += e;
        }
      #pragma unroll
      for (int off = 1; off < 16; off <<= 1)
        #pragma unroll
        for (int q = 0; q < 4; ++q) s[q] += __shfl_xor(s[q], off);
      sm[mi] = s;
    }
    if (r == 0){
      #pragma unroll
      for (int mi = 0; mi < 2; ++mi)
        #pragma unroll
        for (int q = 0; q < 4; ++q)
          smbuf[1][wid][mi*16 + half*4 + q] = sm[mi][q];
    }
    __syncthreads();
    f32x4 inv[2];
    #pragma unroll
    for (int mi = 0; mi < 2; ++mi)
      #pragma unroll
      for (int q = 0; q < 4; ++q){
        int il = mi*16 + half*4 + q;
        float s = smbuf[1][0][il];
        #pragma unroll
        for (int w2 = 1; w2 < 8; ++w2) s += smbuf[1][w2][il];
        inv[mi][q] = 1.0f / s;
      }

    // probs -> Ps[i_local][j] (scalar bf16 writes; 16 r-lanes contiguous)
    #pragma unroll
    for (int mi = 0; mi < 2; ++mi)
      #pragma unroll
      for (int ni = 0; ni < 3; ++ni){
        int j = wid*48 + ni*16 + r;
        #pragma unroll
        for (int q = 0; q < 4; ++q){
          int il = mi*16 + half*4 + q;
          *(u16*)((char*)Ps + swz768(il, j*2)) = f2b(acc[mi][ni][q] * inv[mi][q]);
        }
      }
    __syncthreads();

    // PV: wave -> (i-half mih, d-quarter dq)
    int mih = wid >> 2, dq = wid & 3;
    f32x4 acc2 = {};
    #pragma unroll
    for (int ks = 0; ks < 384; ks += 32){
      int j0 = ks + half*8;
      short8 bfr = *(const short8*)((const char*)Vs + swz768(dq*16 + r, j0*2));
      short8 afr = *(const short8*)((const char*)Ps + swz768(mih*16 + r, j0*2));
      acc2 = MFMA(afr, bfr, acc2);
    }
    #pragma unroll
    for (int q = 0; q < 4; ++q){
      int i = i0s + mih*16 + half*4 + q;
      int d = dq*16 + r;
      ctx[((size_t)(b*384 + i))*512 + h*64 + d] = f2b(acc2[q]);
    }
    __syncthreads();   // Ps/smbuf free for next sub
  }
}

// ---------------- K8: out = ctx @ Wo^T + bo (fp32 out), 64x64 tiles, bf16 staging ----------------
__global__ __launch_bounds__(256) void k_out(const u16* __restrict__ ctx, const u16* __restrict__ Wob,
                                             const float* __restrict__ bo, float* __restrict__ out){
  __shared__ __align__(16) u16 As[64*64];
  __shared__ __align__(16) u16 Bs[64*64];
  int tid = threadIdx.x, lane = tid & 63, wid = tid >> 6;
  int t0 = blockIdx.x * 64, n0 = blockIdx.y * 64;
  f32x4 acc[2][2] = {};
  for (int k0 = 0; k0 < 512; k0 += 64){
    stage_bf16<64>(As, ctx + (size_t)t0*512 + k0, 512, tid);
    stage_bf16<64>(Bs, Wob + (size_t)n0*512 + k0, 512, tid);
    __syncthreads();
    mma_step<2,2>(As, (wid>>1)*32, Bs, (wid&1)*32, acc, lane);
    __syncthreads();
  }
  int r = lane & 15, half = lane >> 4;
  #pragma unroll
  for (int mi = 0; mi < 2; ++mi)
  #pragma unroll
  for (int ni = 0; ni < 2; ++ni){
    int n = n0 + (wid&1)*32 + ni*16 + r;
    int m0 = t0 + (wid>>1)*32 + mi*16 + half*4;
    #pragma unroll
    for (int q = 0; q < 4; ++q){
      int t = m0 + q;
      out[(size_t)t*512 + n] = acc[mi][ni][q] + bo[n];
    }
  }
}

extern "C" void kernel_launch(void* const* d_in, const int* in_sizes, int n_in,
                              void* d_out, int out_size, void* d_ws, size_t ws_size,
                              hipStream_t stream) {
  const float* hs   = (const float*)d_in[0];
  const float* P    = (const float*)d_in[1];
  const int*   mask = (const int*)d_in[2];
  const float* ln_g = (const float*)d_in[3];
  const float* ln_b = (const float*)d_in[4];
  const float* Wq   = (const float*)d_in[5];
  const float* bq   = (const float*)d_in[6];
  const float* Wk   = (const float*)d_in[7];
  const float* bk   = (const float*)d_in[8];
  const float* Wv   = (const float*)d_in[9];
  const float* bv   = (const float*)d_in[10];
  const float* Wpos = (const float*)d_in[11];
  const float* pbu  = (const float*)d_in[12];
  const float* pbv  = (const float*)d_in[13];
  const float* Wo   = (const float*)d_in[14];
  const float* bo   = (const float*)d_in[15];
  float* out = (float*)d_out;

  char* w = (char*)d_ws;
  u16* xbf = (u16*)w;   w += (size_t)3072*512*2;
  u16* qu  = (u16*)w;   w += (size_t)3072*512*2;
  u16* qv  = (u16*)w;   w += (size_t)3072*512*2;
  u16* kkb = (u16*)w;   w += (size_t)3072*512*2;
  u16* vt  = (u16*)w;   w += (size_t)3072*512*2;
  u16* Wpt = (u16*)w;   w += (size_t)8*512*64*2;
  u16* Wqb = (u16*)w;   w += (size_t)512*512*2;
  u16* Wkb = (u16*)w;   w += (size_t)512*512*2;
  u16* Wvb = (u16*)w;   w += (size_t)512*512*2;
  u16* Wob = (u16*)w;   w += (size_t)512*512*2;
  u16* ctx = (u16*)w;   w += (size_t)3072*512*2;
  u16* qW  = (u16*)w;   w += (size_t)64*384*512*2;
  float* Sbd = (float*)w; w += (size_t)64*384*384*4;

  k_prep<<<1088, 256, 0, stream>>>(hs, ln_g, ln_b, Wpos, Wq, Wk, Wv, Wo,
                                   xbf, Wpt, Wqb, Wkb, Wvb, Wob);
  k_qkv<<<dim3(24,4,3), 256, 0, stream>>>(xbf, Wqb, Wkb, Wvb, bq, bk, bv, pbu, pbv, qu, qv, kkb, vt);
  k_qw <<<dim3(24,4,8), 256, 0, stream>>>(qv, Wpt, qW);
  k_bd <<<dim3(2,384), 256, 0, stream>>>(qW, P, Sbd);
  k_fin<<<dim3(4,64), 512, 0, stream>>>(qu, kkb, vt, Sbd, mask, ctx);
  k_out<<<dim3(48,8), 256, 0, stream>>>(ctx, Wob, bo, out);
}

// Round 10
// 158.509 us; speedup vs baseline: 1.4025x; 1.0409x over previous
//
#include <hip/hip_runtime.h>
#include <hip/hip_bf16.h>

#define DEV __device__ __forceinline__

typedef short short8 __attribute__((ext_vector_type(8)));
typedef float f32x4 __attribute__((ext_vector_type(4)));
typedef unsigned short ushort4v __attribute__((ext_vector_type(4)));
typedef unsigned short u16;

DEV u16 f2b(float x){ __hip_bfloat16 h = __float2bfloat16(x); u16 u; __builtin_memcpy(&u, &h, 2); return u; }

// 128B-row LDS tiles, XOR-swizzled (G4).
DEV int swz(int row, int cb){ return row*128 + (cb ^ ((row & 7) << 4)); }
// 768B-row (384 bf16) LDS tiles, XOR-swizzled.
DEV int swz768(int row, int byte_in_row){ return row*768 + (byte_in_row ^ ((row & 7) << 4)); }

DEV short8 ldfrag(const u16* s, int row, int kbf){
  return *(const short8*)((const char*)s + swz(row, kbf*2));
}
DEV void st16(u16* s, int row, int cb, short8 v){
  *(short8*)((char*)s + swz(row, cb)) = v;
}
DEV f32x4 MFMA(short8 a, short8 b, f32x4 c){
  return __builtin_amdgcn_mfma_f32_16x16x32_bf16(a, b, c, 0, 0, 0);
}

template<int R>
DEV void stage_bf16(u16* lds, const u16* g, size_t rstride, int tid){
  #pragma unroll
  for (int c = tid; c < R*8; c += 256){
    int row = c >> 3, k = c & 7;
    short8 v = *(const short8*)(g + (size_t)row*rstride + k*8);
    st16(lds, row, k*16, v);
  }
}

template<int MI, int NI>
DEV void mma_step(const u16* As, int ar0, const u16* Bs, int br0, f32x4 (&acc)[MI][NI], int lane){
  int r = lane & 15, kb = (lane >> 4) * 8;
  #pragma unroll
  for (int kk = 0; kk < 64; kk += 32){
    short8 a[MI], b[NI];
    #pragma unroll
    for (int mi = 0; mi < MI; ++mi) a[mi] = ldfrag(As, ar0 + mi*16 + r, kk + kb);
    #pragma unroll
    for (int ni = 0; ni < NI; ++ni) b[ni] = ldfrag(Bs, br0 + ni*16 + r, kk + kb);
    #pragma unroll
    for (int mi = 0; mi < MI; ++mi)
      #pragma unroll
      for (int ni = 0; ni < NI; ++ni)
        acc[mi][ni] = MFMA(a[mi], b[ni], acc[mi][ni]);
  }
}

// ---------------- K0: prep — LN->xbf, Wpos->Wpt (transpose), W*->bf16 ----------------
__global__ __launch_bounds__(256) void k_prep(const float* __restrict__ hs,
    const float* __restrict__ lg, const float* __restrict__ lb,
    const float* __restrict__ Wpos, const float* __restrict__ Wq, const float* __restrict__ Wk,
    const float* __restrict__ Wv, const float* __restrict__ Wo,
    u16* __restrict__ xbf, u16* __restrict__ Wpt, u16* __restrict__ Wqb,
    u16* __restrict__ Wkb, u16* __restrict__ Wvb, u16* __restrict__ Wob){
  __shared__ float ws[64][65];
  int bx = blockIdx.x, tid = threadIdx.x;
  if (bx < 64){
    int e0 = (bx & 7) * 64, h = bx >> 3;
    #pragma unroll
    for (int p = tid; p < 64*16; p += 256){
      int d = p >> 4, q = p & 15;
      f32x4 v = *(const f32x4*)(Wpos + (size_t)(h*64 + d)*512 + e0 + q*4);
      #pragma unroll
      for (int t = 0; t < 4; ++t) ws[d][q*4+t] = v[t];
    }
    __syncthreads();
    #pragma unroll
    for (int c = tid; c < 64*8; c += 256){
      int e = c >> 3, dc = c & 7;
      short8 v;
      #pragma unroll
      for (int t = 0; t < 8; ++t) v[t] = (short)f2b(ws[dc*8+t][e]);
      *(short8*)(Wpt + ((size_t)h*512 + e0 + e)*64 + dc*8) = v;
    }
  } else if (bx < 320){
    const float* src[4] = {Wq, Wk, Wv, Wo};
    u16* dst[4] = {Wqb, Wkb, Wvb, Wob};
    int base = (bx - 64) * 4096 + tid * 16;
    int m = base >> 18, off = base & ((1<<18)-1);
    const float* s = src[m] + off;
    u16* d = dst[m] + off;
    #pragma unroll
    for (int hh = 0; hh < 2; ++hh){
      f32x4 a = *(const f32x4*)(s + hh*8);
      f32x4 bb = *(const f32x4*)(s + hh*8 + 4);
      short8 v;
      #pragma unroll
      for (int t = 0; t < 4; ++t){ v[t] = (short)f2b(a[t]); v[t+4] = (short)f2b(bb[t]); }
      *(short8*)(d + hh*8) = v;
    }
  } else {
    int lane = tid & 63, wid = tid >> 6;
    int row = (bx - 320) * 4 + wid;
    const float* p = hs + (size_t)row * 512;
    f32x4 v0 = ((const f32x4*)p)[lane];
    f32x4 v1 = ((const f32x4*)p)[lane + 64];
    float s = 0.f, s2 = 0.f;
    #pragma unroll
    for (int t = 0; t < 4; ++t){ s += v0[t] + v1[t]; s2 += v0[t]*v0[t] + v1[t]*v1[t]; }
    #pragma unroll
    for (int off = 32; off; off >>= 1){ s += __shfl_xor(s, off); s2 += __shfl_xor(s2, off); }
    float mu = s * (1.0f/512.0f);
    float var = s2 * (1.0f/512.0f) - mu*mu;
    float rs = rsqrtf(var + 1e-5f);
    int e0 = lane * 4, e1 = 256 + e0;
    ushort4v o0, o1;
    #pragma unroll
    for (int t = 0; t < 4; ++t){
      o0[t] = f2b((v0[t]-mu)*rs*lg[e0+t]+lb[e0+t]);
      o1[t] = f2b((v1[t]-mu)*rs*lg[e1+t]+lb[e1+t]);
    }
    *(ushort4v*)(xbf + (size_t)row*512 + e0) = o0;
    *(ushort4v*)(xbf + (size_t)row*512 + e1) = o1;
  }
}

// ---------------- K2: QKV projection (all-bf16 staging) ----------------
__global__ __launch_bounds__(256) void k_qkv(const u16* __restrict__ xbf,
    const u16* __restrict__ Wqb, const u16* __restrict__ Wkb, const u16* __restrict__ Wvb,
    const float* __restrict__ bq, const float* __restrict__ bk, const float* __restrict__ bv,
    const float* __restrict__ pbu, const float* __restrict__ pbv,
    u16* __restrict__ qu, u16* __restrict__ qv, u16* __restrict__ kkb, u16* __restrict__ vt){
  __shared__ __align__(16) u16 As[128*64];
  __shared__ __align__(16) u16 Bs[128*64];
  int tid = threadIdx.x, lane = tid & 63, wid = tid >> 6;
  int t0 = blockIdx.x * 128, n0 = blockIdx.y * 128, z = blockIdx.z;
  const u16* Wb     = (z==0) ? Wqb : (z==1) ? Wkb : Wvb;
  const float* bias = (z==0) ? bq  : (z==1) ? bk  : bv;
  f32x4 acc[4][4] = {};
  for (int k0 = 0; k0 < 512; k0 += 64){
    stage_bf16<128>(As, xbf + (size_t)t0*512 + k0, 512, tid);
    stage_bf16<128>(Bs, Wb + (size_t)n0*512 + k0, 512, tid);
    __syncthreads();
    mma_step<4,4>(As, (wid>>1)*64, Bs, (wid&1)*64, acc, lane);
    __syncthreads();
  }
  int r = lane & 15, half = lane >> 4;
  #pragma unroll
  for (int mi = 0; mi < 4; ++mi)
  #pragma unroll
  for (int ni = 0; ni < 4; ++ni){
    int n = n0 + (wid&1)*64 + ni*16 + r;
    int h = n >> 6, d = n & 63;
    int m0 = t0 + (wid>>1)*64 + mi*16 + half*4;
    #pragma unroll
    for (int q = 0; q < 4; ++q){
      int t = m0 + q, b = t / 384, i = t - b*384;
      float v = acc[mi][ni][q] + bias[n];
      if (z == 0){
        qu[((size_t)(b*8+h)*384 + i)*64 + d] = f2b(v + pbu[n]);
        qv[((size_t)h*3072 + t)*64 + d]      = f2b(v + pbv[n]);
      } else if (z == 1){
        kkb[((size_t)(b*8+h)*384 + i)*64 + d] = f2b(v);
      } else {
        vt[((size_t)(b*8+h)*64 + d)*384 + i] = f2b(v);
      }
    }
  }
}

// ---------------- K3: qW[bh][j][e] = q_v[h] @ Wpt[h]^T  (K=64) ----------------
__global__ __launch_bounds__(256) void k_qw(const u16* __restrict__ qv, const u16* __restrict__ Wpt,
                                            u16* __restrict__ qW){
  __shared__ __align__(16) u16 As[128*64];
  __shared__ __align__(16) u16 Bs[128*64];
  int tid = threadIdx.x, lane = tid & 63, wid = tid >> 6;
  int t0 = blockIdx.x * 128, e0 = blockIdx.y * 128, h = blockIdx.z;
  f32x4 acc[4][4] = {};
  stage_bf16<128>(As, qv + ((size_t)h*3072 + t0)*64, 64, tid);
  stage_bf16<128>(Bs, Wpt + ((size_t)h*512 + e0)*64, 64, tid);
  __syncthreads();
  mma_step<4,4>(As, (wid>>1)*64, Bs, (wid&1)*64, acc, lane);
  int r = lane & 15, half = lane >> 4;
  #pragma unroll
  for (int mi = 0; mi < 4; ++mi)
  #pragma unroll
  for (int ni = 0; ni < 4; ++ni){
    int e = e0 + (wid&1)*64 + ni*16 + r;
    int m0 = t0 + (wid>>1)*64 + mi*16 + half*4;
    #pragma unroll
    for (int q = 0; q < 4; ++q){
      int t = m0 + q, b = t / 384, j = t - b*384;
      int bh = b*8 + h;
      qW[((size_t)bh*384 + j)*512 + e] = f2b(acc[mi][ni][q]);
    }
  }
}

// ---------------- K5: BD scores per (i-half, j): Sbd[j][bh][i] ----------------
__global__ __launch_bounds__(256, 3) void k_bd(const u16* __restrict__ qW, const float* __restrict__ P,
                                               float* __restrict__ Sbd){
  __shared__ __align__(16) u16 As[64*256];
  int tid = threadIdx.x, lane = tid & 63, wid = tid >> 6;
  int r = lane & 15, half = lane >> 4;
  int ib = blockIdx.x * 192, j = blockIdx.y;

  const float* Bp[3];
  #pragma unroll
  for (int ni = 0; ni < 3; ++ni){
    int i = ib + wid*48 + ni*16 + r;
    Bp[ni] = P + ((size_t)i*384 + j)*512 + half*8;
  }
  const u16* Ag = qW + (size_t)j*512;

  f32x4 acc[4][3] = {};
  #pragma unroll
  for (int kh = 0; kh < 2; ++kh){
    if (kh) __syncthreads();
    #pragma unroll
    for (int s = 0; s < 8; ++s){
      int c = tid + s*256;
      int bh = c >> 5, c16 = c & 31;
      short8 v = *(const short8*)(Ag + (size_t)bh*(384*512) + kh*256 + c16*8);
      *(short8*)((char*)As + bh*512 + ((c16*16) ^ ((bh & 7) << 4))) = v;
    }
    __syncthreads();
    #pragma unroll
    for (int k32 = 0; k32 < 8; ++k32){
      int e0 = kh*256 + k32*32;
      short8 bfr[3];
      #pragma unroll
      for (int ni = 0; ni < 3; ++ni){
        f32x4 f0 = *(const f32x4*)(Bp[ni] + e0);
        f32x4 f1 = *(const f32x4*)(Bp[ni] + e0 + 4);
        #pragma unroll
        for (int t = 0; t < 4; ++t){ bfr[ni][t] = (short)f2b(f0[t]); bfr[ni][t+4] = (short)f2b(f1[t]); }
      }
      #pragma unroll
      for (int mi = 0; mi < 4; ++mi){
        int row = mi*16 + r;
        short8 afr = *(const short8*)((const char*)As + row*512 + ((k32*64 + half*16) ^ ((row & 7) << 4)));
        #pragma unroll
        for (int ni = 0; ni < 3; ++ni)
          acc[mi][ni] = MFMA(afr, bfr[ni], acc[mi][ni]);
      }
    }
  }
  #pragma unroll
  for (int mi = 0; mi < 4; ++mi)
  #pragma unroll
  for (int ni = 0; ni < 3; ++ni){
    int i = ib + wid*48 + ni*16 + r;
    #pragma unroll
    for (int q = 0; q < 4; ++q){
      int bh = mi*16 + half*4 + q;
      Sbd[((size_t)j*64 + bh)*384 + i] = acc[mi][ni][q];
    }
  }
}

// ---------------- K6: fused AC + softmax + PV, 512 threads (R7 layout + hoisted mask + T14 Sbd prefetch) ----------------
__global__ __launch_bounds__(512) void k_fin(const u16* __restrict__ qu, const u16* __restrict__ kkb,
                                             const u16* __restrict__ vt, const float* __restrict__ Sbd,
                                             const int* __restrict__ mask, u16* __restrict__ ctx){
  __shared__ __align__(16) u16 Ks[384*64];
  __shared__ __align__(16) u16 Qs[96*64];
  __shared__ __align__(16) u16 Vs[64*384];
  __shared__ __align__(16) u16 Ps[32*384];
  __shared__ float smbuf[2][8][2][16];
  int tid = threadIdx.x, lane = tid & 63, wid = tid >> 6;
  int r = lane & 15, half = lane >> 4;
  int i0 = blockIdx.x * 96, bh = blockIdx.y, b = bh >> 3, h = bh & 7;

  #pragma unroll
  for (int c = tid; c < 3072; c += 512){
    int row = c >> 3, k = c & 7;
    short8 v = *(const short8*)(kkb + ((size_t)bh*384 + row)*64 + k*8);
    st16(Ks, row, k*16, v);
  }
  #pragma unroll
  for (int c = tid; c < 768; c += 512){
    int row = c >> 3, k = c & 7;
    short8 v = *(const short8*)(qu + ((size_t)bh*384 + i0 + row)*64 + k*8);
    st16(Qs, row, k*16, v);
  }
  #pragma unroll
  for (int c = tid; c < 3072; c += 512){
    int d = c / 48, jc = c - d*48;
    short8 v = *(const short8*)(vt + ((size_t)bh*64 + d)*384 + jc*8);
    *(short8*)((char*)Vs + swz768(d, jc*16)) = v;
  }

  // mask flags are sub-invariant: hoist (j = jw + mi*16 + q)
  int jw = wid*48 + half*4;
  bool dead[3][4];
  #pragma unroll
  for (int mi = 0; mi < 3; ++mi)
    #pragma unroll
    for (int q = 0; q < 4; ++q)
      dead[mi][q] = (mask[b*384 + jw + mi*16 + q] == 0);
  __syncthreads();

  for (int sub = 0; sub < 3; ++sub){
    int i0s = i0 + sub*32;

    // T14: issue Sbd loads BEFORE the QK^T MFMA phase (independent)
    float sv[3][4][2];
    #pragma unroll
    for (int mi = 0; mi < 3; ++mi)
      #pragma unroll
      for (int q = 0; q < 4; ++q){
        const float* srow = Sbd + ((size_t)(jw + mi*16 + q)*64 + bh)*384 + i0s;
        #pragma unroll
        for (int ni = 0; ni < 2; ++ni) sv[mi][q][ni] = srow[ni*16 + r];
      }

    f32x4 acc[3][2] = {};
    mma_step<3,2>(Ks, wid*48, Qs, sub*32, acc, lane);

    #pragma unroll
    for (int mi = 0; mi < 3; ++mi)
      #pragma unroll
      for (int q = 0; q < 4; ++q)
        #pragma unroll
        for (int ni = 0; ni < 2; ++ni){
          float v = (acc[mi][ni][q] + sv[mi][q][ni]) * 0.125f;
          acc[mi][ni][q] = dead[mi][q] ? -3.402823466e38f : v;
        }

    float mx[2];
    #pragma unroll
    for (int ni = 0; ni < 2; ++ni){
      float m = -3.402823466e38f;
      #pragma unroll
      for (int mi = 0; mi < 3; ++mi){
        f32x4 a = acc[mi][ni];
        m = fmaxf(m, fmaxf(fmaxf(a[0],a[1]), fmaxf(a[2],a[3])));
      }
      m = fmaxf(m, __shfl_xor(m, 16));
      m = fmaxf(m, __shfl_xor(m, 32));
      mx[ni] = m;
    }
    if (lane < 16){ smbuf[0][wid][0][r] = mx[0]; smbuf[0][wid][1][r] = mx[1]; }
    __syncthreads();
    #pragma unroll
    for (int ni = 0; ni < 2; ++ni){
      float m = smbuf[0][0][ni][r];
      #pragma unroll
      for (int w2 = 1; w2 < 8; ++w2) m = fmaxf(m, smbuf[0][w2][ni][r]);
      mx[ni] = m;
    }

    float sum[2] = {0.f, 0.f};
    #pragma unroll
    for (int ni = 0; ni < 2; ++ni){
      #pragma unroll
      for (int mi = 0; mi < 3; ++mi)
        #pragma unroll
        for (int q = 0; q < 4; ++q){
          float e = __expf(acc[mi][ni][q] - mx[ni]);
          acc[mi][ni][q] = e; sum[ni] += e;
        }
      sum[ni] += __shfl_xor(sum[ni], 16);
      sum[ni] += __shfl_xor(sum[ni], 32);
    }
    if (lane < 16){ smbuf[1][wid][0][r] = sum[0]; smbuf[1][wid][1][r] = sum[1]; }
    __syncthreads();
    float inv[2];
    #pragma unroll
    for (int ni = 0; ni < 2; ++ni){
      float s = smbuf[1][0][ni][r];
      #pragma unroll
      for (int w2 = 1; w2 < 8; ++w2) s += smbuf[1][w2][ni][r];
      inv[ni] = 1.0f / s;
    }

    #pragma unroll
    for (int mi = 0; mi < 3; ++mi){
      int jb = jw + mi*16;
      #pragma unroll
      for (int ni = 0; ni < 2; ++ni){
        int i = ni*16 + r;
        ushort4v pk;
        #pragma unroll
        for (int q = 0; q < 4; ++q) pk[q] = f2b(acc[mi][ni][q] * inv[ni]);
        *(ushort4v*)((char*)Ps + swz768(i, jb*2)) = pk;
      }
    }
    __syncthreads();

    int mih = wid >> 2, dq = wid & 3;
    f32x4 acc2 = {};
    #pragma unroll
    for (int ks = 0; ks < 384; ks += 32){
      int j0 = ks + half*8;
      short8 bfr = *(const short8*)((const char*)Vs + swz768(dq*16 + r, j0*2));
      short8 afr = *(const short8*)((const char*)Ps + swz768(mih*16 + r, j0*2));
      acc2 = MFMA(afr, bfr, acc2);
    }
    #pragma unroll
    for (int q = 0; q < 4; ++q){
      int i = i0s + mih*16 + half*4 + q;
      int d = dq*16 + r;
      ctx[((size_t)(b*384 + i))*512 + h*64 + d] = f2b(acc2[q]);
    }
    __syncthreads();
  }
}

// ---------------- K8: out = ctx @ Wo^T + bo (fp32 out), 64x64 tiles, bf16 staging ----------------
__global__ __launch_bounds__(256) void k_out(const u16* __restrict__ ctx, const u16* __restrict__ Wob,
                                             const float* __restrict__ bo, float* __restrict__ out){
  __shared__ __align__(16) u16 As[64*64];
  __shared__ __align__(16) u16 Bs[64*64];
  int tid = threadIdx.x, lane = tid & 63, wid = tid >> 6;
  int t0 = blockIdx.x * 64, n0 = blockIdx.y * 64;
  f32x4 acc[2][2] = {};
  for (int k0 = 0; k0 < 512; k0 += 64){
    stage_bf16<64>(As, ctx + (size_t)t0*512 + k0, 512, tid);
    stage_bf16<64>(Bs, Wob + (size_t)n0*512 + k0, 512, tid);
    __syncthreads();
    mma_step<2,2>(As, (wid>>1)*32, Bs, (wid&1)*32, acc, lane);
    __syncthreads();
  }
  int r = lane & 15, half = lane >> 4;
  #pragma unroll
  for (int mi = 0; mi < 2; ++mi)
  #pragma unroll
  for (int ni = 0; ni < 2; ++ni){
    int n = n0 + (wid&1)*32 + ni*16 + r;
    int m0 = t0 + (wid>>1)*32 + mi*16 + half*4;
    #pragma unroll
    for (int q = 0; q < 4; ++q){
      int t = m0 + q;
      out[(size_t)t*512 + n] = acc[mi][ni][q] + bo[n];
    }
  }
}

extern "C" void kernel_launch(void* const* d_in, const int* in_sizes, int n_in,
                              void* d_out, int out_size, void* d_ws, size_t ws_size,
                              hipStream_t stream) {
  const float* hs   = (const float*)d_in[0];
  const float* P    = (const float*)d_in[1];
  const int*   mask = (const int*)d_in[2];
  const float* ln_g = (const float*)d_in[3];
  const float* ln_b = (const float*)d_in[4];
  const float* Wq   = (const float*)d_in[5];
  const float* bq   = (const float*)d_in[6];
  const float* Wk   = (const float*)d_in[7];
  const float* bk   = (const float*)d_in[8];
  const float* Wv   = (const float*)d_in[9];
  const float* bv   = (const float*)d_in[10];
  const float* Wpos = (const float*)d_in[11];
  const float* pbu  = (const float*)d_in[12];
  const float* pbv  = (const float*)d_in[13];
  const float* Wo   = (const float*)d_in[14];
  const float* bo   = (const float*)d_in[15];
  float* out = (float*)d_out;

  char* w = (char*)d_ws;
  u16* xbf = (u16*)w;   w += (size_t)3072*512*2;
  u16* qu  = (u16*)w;   w += (size_t)3072*512*2;
  u16* qv  = (u16*)w;   w += (size_t)3072*512*2;
  u16* kkb = (u16*)w;   w += (size_t)3072*512*2;
  u16* vt  = (u16*)w;   w += (size_t)3072*512*2;
  u16* Wpt = (u16*)w;   w += (size_t)8*512*64*2;
  u16* Wqb = (u16*)w;   w += (size_t)512*512*2;
  u16* Wkb = (u16*)w;   w += (size_t)512*512*2;
  u16* Wvb = (u16*)w;   w += (size_t)512*512*2;
  u16* Wob = (u16*)w;   w += (size_t)512*512*2;
  u16* ctx = (u16*)w;   w += (size_t)3072*512*2;
  u16* qW  = (u16*)w;   w += (size_t)64*384*512*2;
  float* Sbd = (float*)w; w += (size_t)64*384*384*4;

  k_prep<<<1088, 256, 0, stream>>>(hs, ln_g, ln_b, Wpos, Wq, Wk, Wv, Wo,
                                   xbf, Wpt, Wqb, Wkb, Wvb, Wob);
  k_qkv<<<dim3(24,4,3), 256, 0, stream>>>(xbf, Wqb, Wkb, Wvb, bq, bk, bv, pbu, pbv, qu, qv, kkb, vt);
  k_qw <<<dim3(24,4,8), 256, 0, stream>>>(qv, Wpt, qW);
  k_bd <<<dim3(2,384), 256, 0, stream>>>(qW, P, Sbd);
  k_fin<<<dim3(4,64), 512, 0, stream>>>(qu, kkb, vt, Sbd, mask, ctx);
  k_out<<<dim3(48,8), 256, 0, stream>>>(ctx, Wob, bo, out);
}